// Round 12
// baseline (141.640 us; speedup 1.0000x reference)
//
#include <hip/hip_runtime.h>
#include <hip/hip_bf16.h>
#include <math.h>

#define BB 2
#define LL 160
#define NSC 34
#define NS (LL * NSC)      // 5440
#define TOT (BB * NS)      // 10880
#define AD 128
#define ADX 144            // 128 hf channels + {1,x,y,z} + 12 zero rows
#define HID 512
#define NAT 37
#define KC 4               // K-chunk split for hagg phase
#define NVP 1792           // max valid atoms per batch (160 x 11 = 1760, pad to 28*64)
#define NVT 28             // NVP / 64 tiles
#define NVPT (BB * NVP)    // 3584
#define NBLK 224           // grid size: BB*NVT*KC; < 256 CUs -> all co-resident
#define PEN 1.0e9f

typedef __attribute__((ext_vector_type(4))) float f32x4;
typedef __attribute__((ext_vector_type(8))) short s16x8;
typedef __attribute__((address_space(1))) const unsigned int gu32;
typedef __attribute__((address_space(3))) unsigned int lu32;

// global barrier: per-slot cnt and flg on SEPARATE 128B lines; waiters poll with
// a device-scope ACQUIRE LOAD (no RMW -> no line-ownership serialization).
// Slots zeroed by hipMemsetAsync each call.
__device__ __forceinline__ void gbar(int* bar, int idx) {
  __syncthreads();
  if (threadIdx.x == 0) {
    __threadfence();
    int* cnt = bar + idx * 64;        // slot stride 256B
    int* flg = bar + idx * 64 + 32;   // +128B within slot
    if (atomicAdd(cnt, 1) == NBLK - 1) {
      __hip_atomic_store(flg, 1, __ATOMIC_RELEASE, __HIP_MEMORY_SCOPE_AGENT);
    } else {
      while (__hip_atomic_load(flg, __ATOMIC_ACQUIRE, __HIP_MEMORY_SCOPE_AGENT) == 0)
        __builtin_amdgcn_s_sleep(8);
    }
    __threadfence();
  }
  __syncthreads();
}

struct LdsP0 { float t[64][65]; };
struct LdsP1 { int scnt[256]; int sincl[256]; int smap[NVP]; };
struct LdsP2 { __hip_bfloat16 tile[ADX][64]; int sm[64]; };
struct LdsP3 { float4 xs[57 * 9]; __hip_bfloat16 sB[2][4608]; };   // 57 = 14*4+1
struct LdsP4 { __hip_bfloat16 zt[16][136]; float sai[16][4]; float ppart[4][16][3]; };

__global__ __launch_bounds__(256) void k_mega(
    const float* __restrict__ W1, const float* __restrict__ bb,
    const float* __restrict__ aa, const float* __restrict__ mask,
    const float* __restrict__ pm, const float* __restrict__ noise,
    const float* __restrict__ sf, const float* __restrict__ emb,
    const float* __restrict__ b1v, const float* __restrict__ W2,
    const float* __restrict__ b2v,
    float* __restrict__ out_mask, float* __restrict__ out_pos,
    __hip_bfloat16* __restrict__ W1T, float4* __restrict__ ws_xe,
    float* __restrict__ ws_val, int* __restrict__ cg2g,
    float4* __restrict__ xc, __hip_bfloat16* __restrict__ hfTc,
    __hip_bfloat16* __restrict__ ws_z, __hip_bfloat16* __restrict__ haggp,
    float* __restrict__ dgp, int* bar) {
  __shared__ union { LdsP0 p0; LdsP1 p1; LdsP2 p2; LdsP3 p3; LdsP4 p4; } u;
  int tid = threadIdx.x;

  // ---------------- P0: W1T transpose + per-residue prep ----------------
  for (int v = blockIdx.x; v < 32 + BB * LL; v += NBLK) {
    if (v < 32) {
      int j0 = (v >> 2) * 64, c0 = (v & 3) * 64;
      for (int i = tid; i < 64 * 64; i += 256) {
        int jl = i & 63, cl = i >> 6;
        u.p0.t[cl][jl] = W1[(size_t)(c0 + cl) * HID + j0 + jl];
      }
      __syncthreads();
      for (int i = tid; i < 64 * 64; i += 256) {
        int cl = i & 63, jl = i >> 6;
        W1T[(size_t)(j0 + jl) * 256 + c0 + cl] = __float2bfloat16(u.p0.t[cl][jl]);
      }
    } else {
      int bl = v - 32;
      int b = bl / LL, l = bl % LL;
      const float* ap = aa + bl * 20;
      float mv = ap[0]; int rt = 0;
      for (int r = 1; r < 20; ++r) { float vv = ap[r]; if (vv > mv) { mv = vv; rt = r; } }
      float mk = mask[bl];
      const float* pmr = pm + rt * NAT;
      if (tid < NAT) out_mask[bl * NAT + tid] = pmr[tid] * mk;

      float ca0 = bb[(bl * 3 + 1) * 3 + 0] * mk;
      float ca1 = bb[(bl * 3 + 1) * 3 + 1] * mk;
      float ca2 = bb[(bl * 3 + 1) * 3 + 2] * mk;

      if (tid < NSC) {
        float am = pmr[3 + tid] * mk;
        const float* npz = noise + (bl * NSC + tid) * 3;
        float x = ca0 + npz[0], y = ca1 + npz[1], z = ca2 + npz[2];
        float4 xv;
        xv.x = x; xv.y = y; xv.z = z;
        xv.w = x * x + y * y + z * z + (am > 0.f ? 0.f : PEN);
        int g = b * NS + l * NSC + tid;
        ws_xe[g] = xv;
        ws_val[g] = am;
      }
      if (tid < NSC * 3) {
        int s = tid / 3, c = tid % 3;
        float ca = (c == 0) ? ca0 : (c == 1) ? ca1 : ca2;
        float pos = ca + noise[(bl * NSC + s) * 3 + c];
        out_pos[(size_t)(b * NS + l * NSC + s) * 3 + c] = pos;
      }
    }
    __syncthreads();
  }
  gbar(bar, 0);

  // ---------------- P1: scan + compaction maps + compacted x ----------------
  if (blockIdx.x < BB) {
    int b = blockIdx.x;
    int c = 0;
    if (tid < LL) {
      for (int s = 0; s < NSC; ++s)
        if (ws_val[b * NS + tid * NSC + s] > 0.f) ++c;
    }
    u.p1.scnt[tid] = c;
    u.p1.sincl[tid] = c;
    __syncthreads();
    #pragma unroll
    for (int off = 1; off < 256; off <<= 1) {
      int t = (tid >= off) ? u.p1.sincl[tid - off] : 0;
      __syncthreads();
      u.p1.sincl[tid] += t;
      __syncthreads();
    }
    for (int j = tid; j < NVP; j += 256) u.p1.smap[j] = -1;
    __syncthreads();
    if (tid < LL) {
      int o = u.p1.sincl[tid] - c, k = 0;
      for (int s = 0; s < NSC; ++s) {
        int m = tid * NSC + s;
        if (ws_val[b * NS + m] > 0.f) { u.p1.smap[o + k] = m; ++k; }
      }
    }
    __syncthreads();
    for (int j = tid; j < NVP; j += 256) {
      int m = u.p1.smap[j];
      cg2g[b * NVP + j] = m;
      float4 vv;
      if (m >= 0) vv = ws_xe[b * NS + m];
      else { vv.x = 0.f; vv.y = 0.f; vv.z = 0.f; vv.w = PEN; }
      xc[b * NVP + j] = vv;
    }
  }
  gbar(bar, 1);

  // ---------------- P2: compacted hf^T + z hf-half ----------------
  if (blockIdx.x < BB * NVT) {
    int bid = blockIdx.x;
    int b = bid / NVT;
    int j0 = (bid % NVT) * 64;
    if (tid < 64) u.p2.sm[tid] = cg2g[b * NVP + j0 + tid];
    __syncthreads();

    int jl = tid >> 2, cq = tid & 3;
    int m = u.p2.sm[jl];
    union { s16x8 v[4]; __hip_bfloat16 h[32]; } o;
    if (m >= 0) {
      int l = m / NSC, s = m - l * NSC;
      float am = ws_val[b * NS + m];
      const float* sfp = sf + (size_t)(b * LL + l) * AD + cq * 32;
      const float* emp = emb + (size_t)(3 + s) * AD + cq * 32;
      #pragma unroll 8
      for (int k = 0; k < 32; ++k) {
        float hv = (sfp[k] + emp[k] * am) * am;
        o.h[k] = __float2bfloat16(hv);
        u.p2.tile[cq * 32 + k][jl] = o.h[k];
      }
    } else {
      __hip_bfloat16 zz = __float2bfloat16(0.0f);
      #pragma unroll 8
      for (int k = 0; k < 32; ++k) { o.h[k] = zz; u.p2.tile[cq * 32 + k][jl] = zz; }
    }
    {
      __hip_bfloat16* zp = ws_z + ((size_t)(b * NVP + j0 + jl)) * 128 + cq * 32;
      #pragma unroll
      for (int q = 0; q < 4; ++q) *(s16x8*)(zp + q * 8) = o.v[q];
    }
    if (cq == 0) {
      float4 xj = xc[b * NVP + j0 + jl];
      u.p2.tile[128][jl] = __float2bfloat16(m >= 0 ? 1.0f : 0.0f);
      u.p2.tile[129][jl] = __float2bfloat16(xj.x);
      u.p2.tile[130][jl] = __float2bfloat16(xj.y);
      u.p2.tile[131][jl] = __float2bfloat16(xj.z);
      __hip_bfloat16 zz = __float2bfloat16(0.0f);
      for (int rr = 132; rr < ADX; ++rr) u.p2.tile[rr][jl] = zz;
    }
    __syncthreads();
    for (int i = tid; i < ADX * 2; i += 256) {
      int r = i >> 1, hf = i & 1;
      __hip_bfloat16* dst = hfTc + (size_t)b * ADX * NVP + (size_t)r * NVP + j0 + hf * 32;
      const __hip_bfloat16* srow = &u.p2.tile[r][hf * 32];
      #pragma unroll
      for (int q = 0; q < 4; ++q)
        *(s16x8*)(dst + q * 8) = *(const s16x8*)(srow + q * 8);
    }
  }
  gbar(bar, 2);

  // ---------------- P3: compacted (w @ [hf | 1 x y z]) via MFMA ----------------
  {
    constexpr int NSTEP = NVP / 32;                    // 56
    int bid = blockIdx.x;
    int b = bid / (NVT * KC);
    int rem = bid % (NVT * KC);
    int kc = rem / NVT;
    int nt = rem % NVT;
    int n0 = nt * 64;
    int sb = (kc * NSTEP) / KC, se = ((kc + 1) * NSTEP) / KC;
    int w = tid >> 6, lane = tid & 63;
    int ln = lane & 15, g8 = (lane >> 4) * 8;

    const float4* xb = xc + b * NVP;
    const __hip_bfloat16* hb = hfTc + (size_t)b * ADX * NVP;

    int mcnt = (se - sb) * 32;
    for (int i = tid; i < mcnt; i += 256)
      u.p3.xs[(i >> 3) * 9 + (i & 7)] = xb[sb * 32 + i];

    float4 xn = xb[n0 + w * 16 + ln];
    float x2n = xn.w;

    f32x4 acc[9];
    #pragma unroll
    for (int ct = 0; ct < 9; ++ct) acc[ct] = (f32x4){0.f, 0.f, 0.f, 0.f};

    auto STAGE = [&](int s, int pb) {
      const char* srcb = (const char*)(hb + (size_t)s * 32);
      #pragma unroll
      for (int k = 0; k < 3; ++k) {
        int t = tid + k * 256;
        if (t < 576) {
          int row = t >> 2;
          int sl = (t & 3) ^ (row & 3);
          const gu32* gp = (const gu32*)(const void*)(srcb + (size_t)row * (NVP * 2) + sl * 16);
          lu32* lp = (lu32*)(void*)((char*)&u.p3.sB[pb][0] + (size_t)(t & ~63) * 16);
          __builtin_amdgcn_global_load_lds(gp, lp, 16, 0, 0);
        }
      }
    };

    STAGE(sb, 0);
    __syncthreads();

    int cur = 0;
    for (int s = sb; s < se; ++s) {
      if (s + 1 < se) STAGE(s + 1, cur ^ 1);
      int grp = (s - sb) * 4 + (g8 >> 3);
      union { s16x8 v; __hip_bfloat16 h[8]; } af;
      #pragma unroll
      for (int j = 0; j < 8; ++j) {
        float4 xm = u.p3.xs[grp * 9 + j];
        float dt = xn.x * xm.x + xn.y * xm.y + xn.z * xm.z;
        float d2 = x2n + xm.w - 2.f * dt;
        float wv = (d2 < 64.f) ? __expf(d2 * -0.0078125f) : 0.f;
        af.h[j] = __float2bfloat16(wv);
      }
      const char* bbase = (const char*)&u.p3.sB[cur][0];
      int slot = g8 >> 3;
      #pragma unroll
      for (int ct = 0; ct < 9; ++ct) {
        int row = ct * 16 + ln;
        int boff = (row << 6) + ((slot ^ (row & 3)) << 4);
        s16x8 bf = *(const s16x8*)(bbase + boff);
        acc[ct] = __builtin_amdgcn_mfma_f32_16x16x32_bf16(af.v, bf, acc[ct], 0, 0, 0);
      }
      __syncthreads();
      cur ^= 1;
    }

    int q = lane >> 4;
    int grow = b * NVP + n0 + w * 16 + q * 4;
    #pragma unroll
    for (int ct = 0; ct < 8; ++ct)
      #pragma unroll
      for (int r = 0; r < 4; ++r)
        haggp[((size_t)kc * NVPT + grow + r) * AD + ct * 16 + ln] = __float2bfloat16(acc[ct][r]);
    if (ln < 4)
      #pragma unroll
      for (int r = 0; r < 4; ++r)
        dgp[((size_t)kc * NVPT + grow + r) * 4 + ln] = acc[8][r];
  }
  gbar(bar, 3);

  // ---------------- P4: reduce + MLP + gate + scatter (16 rows/block) ----------------
  {
    int r0 = blockIdx.x * 16;
    int w = tid >> 6, lane = tid & 63;
    int ln = lane & 15, g8 = (lane >> 4) * 8, q = lane >> 4;

    if (tid < 16) {
      int g = r0 + tid;
      float deg = 0.f, wx = 0.f, wy = 0.f, wz = 0.f;
      #pragma unroll
      for (int kc = 0; kc < KC; ++kc) {
        float4 d = *(const float4*)&dgp[((size_t)kc * NVPT + g) * 4];
        deg += d.x; wx += d.y; wy += d.z; wz += d.w;
      }
      float inv = 1.f / (deg + 1.f);
      float4 xv = xc[g];
      u.p4.sai[tid][0] = (xv.x * deg - wx) * inv;
      u.p4.sai[tid][1] = (xv.y * deg - wy) * inv;
      u.p4.sai[tid][2] = (xv.z * deg - wz) * inv;
      u.p4.sai[tid][3] = inv;
    }
    __syncthreads();
    {
      int row = tid >> 4, c8 = tid & 15;       // 256 slots = 16 rows x 16
      int g = r0 + row;
      float s[8];
      #pragma unroll
      for (int j = 0; j < 8; ++j) s[j] = 0.f;
      #pragma unroll
      for (int kc = 0; kc < KC; ++kc) {
        union { s16x8 v; __hip_bfloat16 h[8]; } uu;
        uu.v = *(const s16x8*)(haggp + ((size_t)kc * NVPT + g) * AD + c8 * 8);
        #pragma unroll
        for (int j = 0; j < 8; ++j) s[j] += __bfloat162float(uu.h[j]);
      }
      float inv = u.p4.sai[row][3];
      #pragma unroll
      for (int j = 0; j < 8; ++j)
        u.p4.zt[row][c8 * 8 + j] = __float2bfloat16(s[j] * inv);
    }
    __syncthreads();

    int arow = r0 + ln;
    s16x8 a[8];
    #pragma unroll
    for (int kq = 0; kq < 4; ++kq)
      a[kq] = *(const s16x8*)(ws_z + (size_t)arow * 128 + kq * 32 + g8);
    #pragma unroll
    for (int kq = 4; kq < 8; ++kq)
      a[kq] = *(const s16x8*)&u.p4.zt[ln][(kq - 4) * 32 + g8];

    float p[4][3];
    #pragma unroll
    for (int r = 0; r < 4; ++r)
      #pragma unroll
      for (int o = 0; o < 3; ++o) p[r][o] = 0.f;

    #pragma unroll
    for (int jt = 0; jt < 8; ++jt) {
      int j = w * 128 + jt * 16 + ln;
      f32x4 acc = (f32x4){0.f, 0.f, 0.f, 0.f};
      #pragma unroll
      for (int kq = 0; kq < 8; ++kq) {
        s16x8 bw = *(const s16x8*)(W1T + (size_t)j * 256 + kq * 32 + g8);
        acc = __builtin_amdgcn_mfma_f32_16x16x32_bf16(a[kq], bw, acc, 0, 0, 0);
      }
      float bias = b1v[j];
      float w20 = W2[j * 3 + 0], w21 = W2[j * 3 + 1], w22 = W2[j * 3 + 2];
      #pragma unroll
      for (int r = 0; r < 4; ++r) {
        float h = fmaxf(acc[r] + bias, 0.f);
        p[r][0] += h * w20; p[r][1] += h * w21; p[r][2] += h * w22;
      }
    }
    #pragma unroll
    for (int r = 0; r < 4; ++r)
      #pragma unroll
      for (int o = 0; o < 3; ++o) {
        p[r][o] += __shfl_xor(p[r][o], 1);
        p[r][o] += __shfl_xor(p[r][o], 2);
        p[r][o] += __shfl_xor(p[r][o], 4);
        p[r][o] += __shfl_xor(p[r][o], 8);
      }
    if (ln == 0) {
      #pragma unroll
      for (int r = 0; r < 4; ++r) {
        int row = q * 4 + r;
        #pragma unroll
        for (int o = 0; o < 3; ++o) u.p4.ppart[w][row][o] = p[r][o];
      }
    }
    __syncthreads();

    if (tid < 16) {
      int row = tid;
      int g = r0 + row;
      int bq = g / NVP;
      int m = cg2g[g];
      if (m >= 0) {
        float p0 = b2v[0] + u.p4.ppart[0][row][0] + u.p4.ppart[1][row][0] + u.p4.ppart[2][row][0] + u.p4.ppart[3][row][0];
        float p1 = b2v[1] + u.p4.ppart[0][row][1] + u.p4.ppart[1][row][1] + u.p4.ppart[2][row][1] + u.p4.ppart[3][row][1];
        float p2 = b2v[2] + u.p4.ppart[0][row][2] + u.p4.ppart[1][row][2] + u.p4.ppart[2][row][2] + u.p4.ppart[3][row][2];
        float val = ws_val[bq * NS + m];
        float4 xv = xc[g];
        float* op = out_pos + (size_t)(bq * NS + m) * 3;
        op[0] = xv.x + u.p4.sai[row][0] * tanhf(p0) * val;
        op[1] = xv.y + u.p4.sai[row][1] * tanhf(p1) * val;
        op[2] = xv.z + u.p4.sai[row][2] * tanhf(p2) * val;
      }
    }
  }
}

extern "C" void kernel_launch(void* const* d_in, const int* in_sizes, int n_in,
                              void* d_out, int out_size, void* d_ws, size_t ws_size,
                              hipStream_t stream) {
  const float* bb    = (const float*)d_in[0];
  const float* sf    = (const float*)d_in[1];
  const float* aa    = (const float*)d_in[2];
  const float* mask  = (const float*)d_in[4];
  const float* pm    = (const float*)d_in[5];
  const float* emb   = (const float*)d_in[6];
  const float* W1    = (const float*)d_in[7];
  const float* b1v   = (const float*)d_in[8];
  const float* W2    = (const float*)d_in[9];
  const float* b2v   = (const float*)d_in[10];
  const float* noise = (const float*)d_in[11];

  float* out_mask = (float*)d_out;
  float* out_pos  = (float*)d_out + BB * LL * NAT;

  char* cur = (char*)d_ws;
  auto alloc = [&](size_t bytes) -> char* {
    char* p = cur;
    cur += (bytes + 255) & ~(size_t)255;
    return p;
  };
  int*    bar    = (int*)alloc(1024);                  // 4 slots x 256B (cnt/flg on separate lines)
  float4* ws_xe  = (float4*)alloc((size_t)TOT * 16);
  float*  ws_val = (float*)alloc((size_t)TOT * 4);
  int*    cg2g   = (int*)alloc((size_t)BB * NVP * 4);
  float4* xc     = (float4*)alloc((size_t)BB * NVP * 16);
  float*  ws_dgp = (float*)alloc((size_t)KC * NVPT * 16);
  __hip_bfloat16* ws_w1t = (__hip_bfloat16*)alloc((size_t)HID * 256 * 2);
  __hip_bfloat16* hfTc   = (__hip_bfloat16*)alloc((size_t)BB * ADX * NVP * 2);
  __hip_bfloat16* haggp  = (__hip_bfloat16*)alloc((size_t)KC * NVPT * AD * 2);
  __hip_bfloat16* ws_z   = (__hip_bfloat16*)alloc((size_t)NVPT * 128 * 2);

  hipMemsetAsync(bar, 0, 1024, stream);
  hipLaunchKernelGGL(k_mega, dim3(NBLK), dim3(256), 0, stream,
                     W1, bb, aa, mask, pm, noise, sf, emb, b1v, W2, b2v,
                     out_mask, out_pos, ws_w1t, ws_xe, ws_val, cg2g, xc,
                     hfTc, ws_z, haggp, ws_dgp, bar);
}

// Round 13
// 53.747 us; speedup vs baseline: 2.6353x; 2.6353x over previous
//
#include <hip/hip_runtime.h>
#include <hip/hip_bf16.h>
#include <math.h>

#define BB 2
#define LL 160
#define NSC 34
#define NS (LL * NSC)      // 5440
#define TOT (BB * NS)      // 10880
#define AD 128
#define ADX 144            // 128 hf channels + {1,x,y,z} + 12 zero rows
#define HID 512
#define NAT 37
#define KC 8               // K-chunk split for k_haggc
#define NVP 1792           // max valid atoms per batch (160 x 11 = 1760, pad to 28*64)
#define NVT 28             // NVP / 64 tiles
#define NVPT (BB * NVP)    // 3584
#define PEN 1.0e9f

typedef __attribute__((ext_vector_type(4))) float f32x4;
typedef __attribute__((ext_vector_type(8))) short s16x8;
typedef __attribute__((address_space(1))) const unsigned int gu32;
typedef __attribute__((address_space(3))) unsigned int lu32;

// ---------------- K1: fused W1-transpose (blocks 0..31) + per-residue prep ----------------
__global__ __launch_bounds__(256) void k_pre(
    const float* __restrict__ W1, __hip_bfloat16* __restrict__ W1T,
    const float* __restrict__ bb, const float* __restrict__ aa,
    const float* __restrict__ mask, const float* __restrict__ pm,
    const float* __restrict__ noise,
    float* __restrict__ out_mask, float4* __restrict__ ws_xe,
    float* __restrict__ ws_val, float* __restrict__ out_pos) {
  __shared__ float t[64][65];
  int blk = blockIdx.x;
  int tid = threadIdx.x;
  if (blk < 32) {
    int j0 = (blk >> 2) * 64;
    int c0 = (blk & 3) * 64;
    for (int i = tid; i < 64 * 64; i += 256) {
      int jl = i & 63, cl = i >> 6;
      t[cl][jl] = W1[(size_t)(c0 + cl) * HID + j0 + jl];
    }
    __syncthreads();
    for (int i = tid; i < 64 * 64; i += 256) {
      int cl = i & 63, jl = i >> 6;
      W1T[(size_t)(j0 + jl) * 256 + c0 + cl] = __float2bfloat16(t[cl][jl]);
    }
    return;
  }
  int bl = blk - 32;                 // b*L + l
  int b = bl / LL, l = bl % LL;
  const float* ap = aa + bl * 20;
  float mv = ap[0]; int rt = 0;
  for (int r = 1; r < 20; ++r) { float v = ap[r]; if (v > mv) { mv = v; rt = r; } }
  float mk = mask[bl];
  const float* pmr = pm + rt * NAT;
  if (tid < NAT) out_mask[bl * NAT + tid] = pmr[tid] * mk;

  float ca0 = bb[(bl * 3 + 1) * 3 + 0] * mk;
  float ca1 = bb[(bl * 3 + 1) * 3 + 1] * mk;
  float ca2 = bb[(bl * 3 + 1) * 3 + 2] * mk;

  if (tid < NSC) {
    float am = pmr[3 + tid] * mk;   // includes atom-3 backbone slot (s=0)
    const float* npz = noise + (bl * NSC + tid) * 3;
    float x = ca0 + npz[0], y = ca1 + npz[1], z = ca2 + npz[2];
    float4 xv;
    xv.x = x; xv.y = y; xv.z = z;
    xv.w = x * x + y * y + z * z + (am > 0.f ? 0.f : PEN);
    int g = b * NS + l * NSC + tid;
    ws_xe[g] = xv;
    ws_val[g] = am;
  }
  if (tid < NSC * 3) {              // default out_pos = pos (overwritten for valid atoms)
    int s = tid / 3, c = tid % 3;
    float ca = (c == 0) ? ca0 : (c == 1) ? ca1 : ca2;
    float pos = ca + noise[(bl * NSC + s) * 3 + c];
    out_pos[(size_t)(b * NS + l * NSC + s) * 3 + c] = pos;
  }
}

// ---------------- K2: per-block redundant scan + compacted hf^T + z hf-half ----------------
// grid = BB*NVT (64 compacted slots each), 256 threads.
// Each block recomputes its batch's compaction scan in LDS (redundant but
// parallel), then writes cg2g/xc for its own 64 slots + hfTc/z tiles.
__global__ __launch_bounds__(256) void k_prep1c(
    const float* __restrict__ sf, const float* __restrict__ emb,
    const float* __restrict__ ws_val, const float4* __restrict__ ws_xe,
    int* __restrict__ cg2g, float4* __restrict__ xc,
    __hip_bfloat16* __restrict__ hfTc, __hip_bfloat16* __restrict__ ws_z) {
  __shared__ int sincl[256];
  __shared__ int smap[NVP];
  __shared__ __hip_bfloat16 tile[ADX][64];
  int bid = blockIdx.x;
  int b = bid / NVT;
  int j0 = (bid % NVT) * 64;
  int tid = threadIdx.x;

  // --- scan (Hillis-Steele over residue valid-counts) ---
  int c = 0;
  if (tid < LL) {
    for (int s = 0; s < NSC; ++s)
      if (ws_val[b * NS + tid * NSC + s] > 0.f) ++c;
  }
  sincl[tid] = c;
  __syncthreads();
  #pragma unroll
  for (int off = 1; off < 256; off <<= 1) {
    int t = (tid >= off) ? sincl[tid - off] : 0;
    __syncthreads();
    sincl[tid] += t;
    __syncthreads();
  }
  for (int j = tid; j < NVP; j += 256) smap[j] = -1;
  __syncthreads();
  if (tid < LL) {
    int o = sincl[tid] - c, k = 0;
    for (int s = 0; s < NSC; ++s) {
      int m = tid * NSC + s;
      if (ws_val[b * NS + m] > 0.f) { smap[o + k] = m; ++k; }
    }
  }
  __syncthreads();

  // --- write cg2g + xc for own 64 slots ---
  if (tid < 64) {
    int j = j0 + tid;
    int m = smap[j];
    cg2g[b * NVP + j] = m;
    float4 v;
    if (m >= 0) v = ws_xe[b * NS + m];
    else { v.x = 0.f; v.y = 0.f; v.z = 0.f; v.w = PEN; }
    xc[b * NVP + j] = v;
  }

  int jl = tid >> 2, cq = tid & 3;
  int m = smap[j0 + jl];
  union { s16x8 v[4]; __hip_bfloat16 h[32]; } o;
  if (m >= 0) {
    int l = m / NSC, s = m - l * NSC;
    float am = ws_val[b * NS + m];
    const float* sfp = sf + (size_t)(b * LL + l) * AD + cq * 32;
    const float* emp = emb + (size_t)(3 + s) * AD + cq * 32;
    #pragma unroll 8
    for (int k = 0; k < 32; ++k) {
      float hv = (sfp[k] + emp[k] * am) * am;
      o.h[k] = __float2bfloat16(hv);
      tile[cq * 32 + k][jl] = o.h[k];
    }
  } else {
    __hip_bfloat16 zz = __float2bfloat16(0.0f);
    #pragma unroll 8
    for (int k = 0; k < 32; ++k) { o.h[k] = zz; tile[cq * 32 + k][jl] = zz; }
  }
  // z hf-half row-major [NVPT][128]
  {
    __hip_bfloat16* zp = ws_z + ((size_t)(b * NVP + j0 + jl)) * 128 + cq * 32;
    #pragma unroll
    for (int q = 0; q < 4; ++q) *(s16x8*)(zp + q * 8) = o.v[q];
  }
  if (cq == 0) {
    float xjx = 0.f, xjy = 0.f, xjz = 0.f;
    if (m >= 0) {
      float4 xj = ws_xe[b * NS + m];
      xjx = xj.x; xjy = xj.y; xjz = xj.z;
    }
    tile[128][jl] = __float2bfloat16(m >= 0 ? 1.0f : 0.0f);
    tile[129][jl] = __float2bfloat16(xjx);
    tile[130][jl] = __float2bfloat16(xjy);
    tile[131][jl] = __float2bfloat16(xjz);
    __hip_bfloat16 zz = __float2bfloat16(0.0f);
    for (int rr = 132; rr < ADX; ++rr) tile[rr][jl] = zz;
  }
  __syncthreads();
  // stream out: 144 rows x 64 cols
  for (int i = tid; i < ADX * 2; i += 256) {
    int r = i >> 1, hf = i & 1;
    __hip_bfloat16* dst = hfTc + (size_t)b * ADX * NVP + (size_t)r * NVP + j0 + hf * 32;
    const __hip_bfloat16* srow = &tile[r][hf * 32];
    #pragma unroll
    for (int q = 0; q < 4; ++q)
      *(s16x8*)(dst + q * 8) = *(const s16x8*)(srow + q * 8);
  }
}

// ---------------- K3: compacted (w @ [hf | 1 x y z]) via MFMA bf16 ----------------
// grid = BB * NVT * KC = 448, 256 threads; 64 rows/block, 4 waves row-split
__global__ __launch_bounds__(256, 4) void k_haggc(
    const float4* __restrict__ xc, const __hip_bfloat16* __restrict__ hfTc,
    __hip_bfloat16* __restrict__ haggp, float* __restrict__ dgp) {
  constexpr int NSTEP = NVP / 32;                    // 56
  constexpr int CH_MAX = (NSTEP + KC - 1) / KC;      // 7
  __shared__ float4 xs[(CH_MAX * 4 + 1) * 9];        // padded: group stride 9
  __shared__ alignas(16) __hip_bfloat16 sB[2][4608]; // 2 x 144 rows x 32 bf16

  int bid = blockIdx.x;
  int b = bid / (NVT * KC);
  int rem = bid % (NVT * KC);
  int kc = rem / NVT;
  int nt = rem % NVT;
  int n0 = nt * 64;
  int sb = (kc * NSTEP) / KC, se = ((kc + 1) * NSTEP) / KC;
  int tid = threadIdx.x, w = tid >> 6, lane = tid & 63;
  int ln = lane & 15, g8 = (lane >> 4) * 8;

  const float4* xb = xc + b * NVP;
  const __hip_bfloat16* hb = hfTc + (size_t)b * ADX * NVP;

  int mcnt = (se - sb) * 32;
  for (int i = tid; i < mcnt; i += 256)
    xs[(i >> 3) * 9 + (i & 7)] = xb[sb * 32 + i];

  float4 xn = xb[n0 + w * 16 + ln];
  float x2n = xn.w;

  f32x4 acc[9];
  #pragma unroll
  for (int ct = 0; ct < 9; ++ct) acc[ct] = (f32x4){0.f, 0.f, 0.f, 0.f};

  auto STAGE = [&](int s, int pb) {
    const char* srcb = (const char*)(hb + (size_t)s * 32);
    #pragma unroll
    for (int k = 0; k < 3; ++k) {
      int t = tid + k * 256;
      if (t < 576) {
        int row = t >> 2;
        int sl = (t & 3) ^ (row & 3);
        const gu32* gp = (const gu32*)(const void*)(srcb + (size_t)row * (NVP * 2) + sl * 16);
        lu32* lp = (lu32*)(void*)((char*)&sB[pb][0] + (size_t)(t & ~63) * 16);
        __builtin_amdgcn_global_load_lds(gp, lp, 16, 0, 0);
      }
    }
  };

  STAGE(sb, 0);
  __syncthreads();

  int cur = 0;
  for (int s = sb; s < se; ++s) {
    if (s + 1 < se) STAGE(s + 1, cur ^ 1);
    int grp = (s - sb) * 4 + (g8 >> 3);
    union { s16x8 v; __hip_bfloat16 h[8]; } af;
    #pragma unroll
    for (int j = 0; j < 8; ++j) {
      float4 xm = xs[grp * 9 + j];
      float dt = xn.x * xm.x + xn.y * xm.y + xn.z * xm.z;
      float d2 = x2n + xm.w - 2.f * dt;
      float wv = (d2 < 64.f) ? __expf(d2 * -0.0078125f) : 0.f;
      af.h[j] = __float2bfloat16(wv);
    }
    const char* bbase = (const char*)&sB[cur][0];
    int slot = g8 >> 3;
    #pragma unroll
    for (int ct = 0; ct < 9; ++ct) {
      int row = ct * 16 + ln;
      int boff = (row << 6) + ((slot ^ (row & 3)) << 4);
      s16x8 bf = *(const s16x8*)(bbase + boff);
      acc[ct] = __builtin_amdgcn_mfma_f32_16x16x32_bf16(af.v, bf, acc[ct], 0, 0, 0);
    }
    __syncthreads();
    cur ^= 1;
  }

  int q = lane >> 4;
  int grow = b * NVP + n0 + w * 16 + q * 4;
  #pragma unroll
  for (int ct = 0; ct < 8; ++ct)
    #pragma unroll
    for (int r = 0; r < 4; ++r)
      haggp[((size_t)kc * NVPT + grow + r) * AD + ct * 16 + ln] = __float2bfloat16(acc[ct][r]);
  if (ln < 4)
    #pragma unroll
    for (int r = 0; r < 4; ++r)
      dgp[((size_t)kc * NVPT + grow + r) * 4 + ln] = acc[8][r];
}

// ---------------- K4: fused reduce + MLP + gate + scatter (8-wave) ----------------
// grid = NVPT/32 = 112 blocks, 512 threads:
// wave = (js4 = w>>1 in 0..3: 128 hidden units) x (rowhalf = w&1: 16 rows)
__global__ __launch_bounds__(512) void k_mlpf(
    const __hip_bfloat16* __restrict__ ws_z,
    const __hip_bfloat16* __restrict__ haggp, const float* __restrict__ dgp,
    const __hip_bfloat16* __restrict__ W1T, const float* __restrict__ b1v,
    const float* __restrict__ W2, const float* __restrict__ b2v,
    const float4* __restrict__ xc, const int* __restrict__ cg2g,
    const float* __restrict__ ws_val, float* __restrict__ out_pos) {
  __shared__ __hip_bfloat16 zt[32][136];   // hagg half, padded stride
  __shared__ float sai[32][4];             // agg_pos*inv, inv
  __shared__ float ppart[4][32][3];        // per-js4 partials

  int r0 = blockIdx.x * 32;
  int tid = threadIdx.x, w = tid >> 6, lane = tid & 63;
  int ln = lane & 15, g8 = (lane >> 4) * 8, q = lane >> 4;
  int rowhalf = w & 1, js4 = w >> 1;

  if (tid < 32) {
    int g = r0 + tid;
    float deg = 0.f, wx = 0.f, wy = 0.f, wz = 0.f;
    #pragma unroll
    for (int kc = 0; kc < KC; ++kc) {
      float4 d = *(const float4*)&dgp[((size_t)kc * NVPT + g) * 4];
      deg += d.x; wx += d.y; wy += d.z; wz += d.w;
    }
    float inv = 1.f / (deg + 1.f);
    float4 xv = xc[g];
    sai[tid][0] = (xv.x * deg - wx) * inv;
    sai[tid][1] = (xv.y * deg - wy) * inv;
    sai[tid][2] = (xv.z * deg - wz) * inv;
    sai[tid][3] = inv;
  }
  __syncthreads();
  {
    int row = tid >> 4, c8 = tid & 15;     // 512 slots exactly
    int g = r0 + row;
    float s[8];
    #pragma unroll
    for (int j = 0; j < 8; ++j) s[j] = 0.f;
    #pragma unroll
    for (int kc = 0; kc < KC; ++kc) {
      union { s16x8 v; __hip_bfloat16 h[8]; } uu;
      uu.v = *(const s16x8*)(haggp + ((size_t)kc * NVPT + g) * AD + c8 * 8);
      #pragma unroll
      for (int j = 0; j < 8; ++j) s[j] += __bfloat162float(uu.h[j]);
    }
    float inv = sai[row][3];
    #pragma unroll
    for (int j = 0; j < 8; ++j)
      zt[row][c8 * 8 + j] = __float2bfloat16(s[j] * inv);
  }
  __syncthreads();

  int arl = rowhalf * 16 + ln;
  int arow = r0 + arl;
  s16x8 a[8];
  #pragma unroll
  for (int kq = 0; kq < 4; ++kq)
    a[kq] = *(const s16x8*)(ws_z + (size_t)arow * 128 + kq * 32 + g8);
  #pragma unroll
  for (int kq = 4; kq < 8; ++kq)
    a[kq] = *(const s16x8*)&zt[arl][(kq - 4) * 32 + g8];

  float p[4][3];
  #pragma unroll
  for (int r = 0; r < 4; ++r)
    #pragma unroll
    for (int o = 0; o < 3; ++o) p[r][o] = 0.f;

  #pragma unroll
  for (int jt = 0; jt < 8; ++jt) {
    int j = js4 * 128 + jt * 16 + ln;
    f32x4 acc = (f32x4){0.f, 0.f, 0.f, 0.f};
    #pragma unroll
    for (int kq = 0; kq < 8; ++kq) {
      s16x8 bw = *(const s16x8*)(W1T + (size_t)j * 256 + kq * 32 + g8);
      acc = __builtin_amdgcn_mfma_f32_16x16x32_bf16(a[kq], bw, acc, 0, 0, 0);
    }
    float bias = b1v[j];
    float w20 = W2[j * 3 + 0], w21 = W2[j * 3 + 1], w22 = W2[j * 3 + 2];
    #pragma unroll
    for (int r = 0; r < 4; ++r) {
      float h = fmaxf(acc[r] + bias, 0.f);
      p[r][0] += h * w20; p[r][1] += h * w21; p[r][2] += h * w22;
    }
  }
  #pragma unroll
  for (int r = 0; r < 4; ++r)
    #pragma unroll
    for (int o = 0; o < 3; ++o) {
      p[r][o] += __shfl_xor(p[r][o], 1);
      p[r][o] += __shfl_xor(p[r][o], 2);
      p[r][o] += __shfl_xor(p[r][o], 4);
      p[r][o] += __shfl_xor(p[r][o], 8);
    }
  if (ln == 0) {
    #pragma unroll
    for (int r = 0; r < 4; ++r) {
      int row = rowhalf * 16 + q * 4 + r;
      #pragma unroll
      for (int o = 0; o < 3; ++o) ppart[js4][row][o] = p[r][o];
    }
  }
  __syncthreads();

  if (tid < 32) {
    int row = tid;
    int g = r0 + row;
    int bq = g / NVP;
    int m = cg2g[g];
    if (m >= 0) {
      float p0 = b2v[0] + ppart[0][row][0] + ppart[1][row][0] + ppart[2][row][0] + ppart[3][row][0];
      float p1 = b2v[1] + ppart[0][row][1] + ppart[1][row][1] + ppart[2][row][1] + ppart[3][row][1];
      float p2 = b2v[2] + ppart[0][row][2] + ppart[1][row][2] + ppart[2][row][2] + ppart[3][row][2];
      float val = ws_val[bq * NS + m];
      float4 xv = xc[g];
      float* op = out_pos + (size_t)(bq * NS + m) * 3;
      op[0] = xv.x + sai[row][0] * tanhf(p0) * val;
      op[1] = xv.y + sai[row][1] * tanhf(p1) * val;
      op[2] = xv.z + sai[row][2] * tanhf(p2) * val;
    }
  }
}

extern "C" void kernel_launch(void* const* d_in, const int* in_sizes, int n_in,
                              void* d_out, int out_size, void* d_ws, size_t ws_size,
                              hipStream_t stream) {
  const float* bb    = (const float*)d_in[0];
  const float* sf    = (const float*)d_in[1];
  const float* aa    = (const float*)d_in[2];
  const float* mask  = (const float*)d_in[4];
  const float* pm    = (const float*)d_in[5];
  const float* emb   = (const float*)d_in[6];
  const float* W1    = (const float*)d_in[7];
  const float* b1v   = (const float*)d_in[8];
  const float* W2    = (const float*)d_in[9];
  const float* b2v   = (const float*)d_in[10];
  const float* noise = (const float*)d_in[11];

  float* out_mask = (float*)d_out;
  float* out_pos  = (float*)d_out + BB * LL * NAT;

  char* cur = (char*)d_ws;
  auto alloc = [&](size_t bytes) -> char* {
    char* p = cur;
    cur += (bytes + 255) & ~(size_t)255;
    return p;
  };
  float4* ws_xe  = (float4*)alloc((size_t)TOT * 16);
  float*  ws_val = (float*)alloc((size_t)TOT * 4);
  int*    cg2g   = (int*)alloc((size_t)BB * NVP * 4);
  float4* xc     = (float4*)alloc((size_t)BB * NVP * 16);
  float*  ws_dgp = (float*)alloc((size_t)KC * NVPT * 16);
  __hip_bfloat16* ws_w1t = (__hip_bfloat16*)alloc((size_t)HID * 256 * 2);
  __hip_bfloat16* hfTc   = (__hip_bfloat16*)alloc((size_t)BB * ADX * NVP * 2);
  __hip_bfloat16* haggp  = (__hip_bfloat16*)alloc((size_t)KC * NVPT * AD * 2);
  __hip_bfloat16* ws_z   = (__hip_bfloat16*)alloc((size_t)NVPT * 128 * 2);

  hipLaunchKernelGGL(k_pre, dim3(32 + BB * LL), dim3(256), 0, stream,
                     W1, ws_w1t, bb, aa, mask, pm, noise,
                     out_mask, ws_xe, ws_val, out_pos);
  hipLaunchKernelGGL(k_prep1c, dim3(BB * NVT), dim3(256), 0, stream,
                     sf, emb, ws_val, ws_xe, cg2g, xc, hfTc, ws_z);
  hipLaunchKernelGGL(k_haggc, dim3(BB * NVT * KC), dim3(256), 0, stream,
                     xc, hfTc, haggp, ws_dgp);
  hipLaunchKernelGGL(k_mlpf, dim3(NVPT / 32), dim3(512), 0, stream,
                     ws_z, haggp, ws_dgp, ws_w1t, b1v, W2, b2v,
                     xc, cg2g, ws_val, out_pos);
}

// Round 14
// 47.256 us; speedup vs baseline: 2.9973x; 1.1374x over previous
//
#include <hip/hip_runtime.h>
#include <hip/hip_bf16.h>
#include <math.h>

#define BB 2
#define LL 160
#define NSC 34
#define NS (LL * NSC)      // 5440
#define TOT (BB * NS)      // 10880
#define AD 128
#define ADX 144            // 128 hf channels + {1,x,y,z} + 12 zero rows
#define HID 512
#define NAT 37
#define KC 8               // K-chunk split for k_haggc
#define NVP 1792           // max valid atoms per batch (160 x 11 = 1760, pad to 28*64)
#define NVT 28             // NVP / 64 tiles
#define NVPT (BB * NVP)    // 3584
#define PEN 1.0e9f

typedef __attribute__((ext_vector_type(4))) float f32x4;
typedef __attribute__((ext_vector_type(8))) short s16x8;
typedef __attribute__((address_space(1))) const unsigned int gu32;
typedef __attribute__((address_space(3))) unsigned int lu32;

struct LdsW { float t[64][65]; };
struct LdsPC {
  int sincl[256];
  int smap[NVP];
  short srt[LL];
  float smk[LL];
  float4 sxc[64];
  __hip_bfloat16 tile[ADX][64];
};

// ---------------- K1: W1T (blk<32) | residue prep (32..351) | compact tiles (352..407) ----------------
__global__ __launch_bounds__(256) void k_prep(
    const float* __restrict__ W1, const float* __restrict__ bb,
    const float* __restrict__ aa, const float* __restrict__ mask,
    const float* __restrict__ pm, const float* __restrict__ noise,
    const float* __restrict__ sf, const float* __restrict__ emb,
    float* __restrict__ out_mask, float* __restrict__ out_pos,
    __hip_bfloat16* __restrict__ W1T, float* __restrict__ ws_val,
    int* __restrict__ cg2g, float4* __restrict__ xc,
    __hip_bfloat16* __restrict__ hfTc, __hip_bfloat16* __restrict__ ws_z,
    int* __restrict__ ws_nv) {
  __shared__ union { LdsW w; LdsPC c; } u;
  int blk = blockIdx.x;
  int tid = threadIdx.x;

  if (blk < 32) {                       // ---- W1 transpose -> bf16 [HID][256]
    int j0 = (blk >> 2) * 64;
    int c0 = (blk & 3) * 64;
    for (int i = tid; i < 64 * 64; i += 256) {
      int jl = i & 63, cl = i >> 6;
      u.w.t[cl][jl] = W1[(size_t)(c0 + cl) * HID + j0 + jl];
    }
    __syncthreads();
    for (int i = tid; i < 64 * 64; i += 256) {
      int cl = i & 63, jl = i >> 6;
      W1T[(size_t)(j0 + jl) * 256 + c0 + cl] = __float2bfloat16(u.w.t[cl][jl]);
    }
    return;
  }

  if (blk < 32 + BB * LL) {             // ---- per-residue prep
    int bl = blk - 32;
    int b = bl / LL, l = bl % LL;
    const float* ap = aa + bl * 20;
    float mv = ap[0]; int rt = 0;
    for (int r = 1; r < 20; ++r) { float v = ap[r]; if (v > mv) { mv = v; rt = r; } }
    float mk = mask[bl];
    const float* pmr = pm + rt * NAT;
    if (tid < NAT) out_mask[bl * NAT + tid] = pmr[tid] * mk;
    if (tid < NSC) ws_val[b * NS + l * NSC + tid] = pmr[3 + tid] * mk;
    float ca0 = bb[(bl * 3 + 1) * 3 + 0] * mk;
    float ca1 = bb[(bl * 3 + 1) * 3 + 1] * mk;
    float ca2 = bb[(bl * 3 + 1) * 3 + 2] * mk;
    if (tid < NSC * 3) {                // default out_pos (valid atoms overwritten in K3)
      int s = tid / 3, c = tid % 3;
      float ca = (c == 0) ? ca0 : (c == 1) ? ca1 : ca2;
      out_pos[(size_t)(b * NS + l * NSC + s) * 3 + c] = ca + noise[(bl * NSC + s) * 3 + c];
    }
    return;
  }

  // ---- compacted tiles: self-contained scan + hf^T + z hf-half + xc/cg2g/nv
  int pb = blk - (32 + BB * LL);
  int b = pb / NVT;
  int j0 = (pb % NVT) * 64;

  int c = 0;
  if (tid < LL) {
    int bl = b * LL + tid;
    const float* ap = aa + bl * 20;
    float mv = ap[0]; int rt = 0;
    for (int r = 1; r < 20; ++r) { float v = ap[r]; if (v > mv) { mv = v; rt = r; } }
    float mk = mask[bl];
    u.c.srt[tid] = (short)rt;
    u.c.smk[tid] = mk;
    const float* pmr = pm + rt * NAT + 3;
    for (int s = 0; s < NSC; ++s)
      if (pmr[s] * mk > 0.f) ++c;
  }
  u.c.sincl[tid] = c;
  __syncthreads();
  #pragma unroll
  for (int off = 1; off < 256; off <<= 1) {
    int t = (tid >= off) ? u.c.sincl[tid - off] : 0;
    __syncthreads();
    u.c.sincl[tid] += t;
    __syncthreads();
  }
  if (tid == 0 && j0 == 0) ws_nv[b] = u.c.sincl[LL - 1];
  for (int j = tid; j < NVP; j += 256) u.c.smap[j] = -1;
  __syncthreads();
  if (tid < LL) {
    int o = u.c.sincl[tid] - c, k = 0;
    const float* pmr = pm + (int)u.c.srt[tid] * NAT + 3;
    float mk = u.c.smk[tid];
    for (int s = 0; s < NSC; ++s) {
      if (pmr[s] * mk > 0.f) { u.c.smap[o + k] = tid * NSC + s; ++k; }
    }
  }
  __syncthreads();

  if (tid < 64) {
    int j = j0 + tid;
    int m = u.c.smap[j];
    cg2g[b * NVP + j] = m;
    float4 v;
    if (m >= 0) {
      int l = m / NSC, s = m - l * NSC;
      float mk = u.c.smk[l];
      int bl = b * LL + l;
      const float* npz = noise + (bl * NSC + s) * 3;
      float x = bb[(bl * 3 + 1) * 3 + 0] * mk + npz[0];
      float y = bb[(bl * 3 + 1) * 3 + 1] * mk + npz[1];
      float z = bb[(bl * 3 + 1) * 3 + 2] * mk + npz[2];
      v.x = x; v.y = y; v.z = z;
      v.w = x * x + y * y + z * z;
    } else {
      v.x = 0.f; v.y = 0.f; v.z = 0.f; v.w = PEN;
    }
    xc[b * NVP + j] = v;
    u.c.sxc[tid] = v;
  }
  __syncthreads();

  int jl = tid >> 2, cq = tid & 3;
  int m = u.c.smap[j0 + jl];
  union { s16x8 v[4]; __hip_bfloat16 h[32]; } o;
  if (m >= 0) {
    int l = m / NSC, s = m - l * NSC;
    float am = pm[(int)u.c.srt[l] * NAT + 3 + s] * u.c.smk[l];
    const float* sfp = sf + (size_t)(b * LL + l) * AD + cq * 32;
    const float* emp = emb + (size_t)(3 + s) * AD + cq * 32;
    #pragma unroll 8
    for (int k = 0; k < 32; ++k) {
      float hv = (sfp[k] + emp[k] * am) * am;
      o.h[k] = __float2bfloat16(hv);
      u.c.tile[cq * 32 + k][jl] = o.h[k];
    }
  } else {
    __hip_bfloat16 zz = __float2bfloat16(0.0f);
    #pragma unroll 8
    for (int k = 0; k < 32; ++k) { o.h[k] = zz; u.c.tile[cq * 32 + k][jl] = zz; }
  }
  {
    __hip_bfloat16* zp = ws_z + ((size_t)(b * NVP + j0 + jl)) * 128 + cq * 32;
    #pragma unroll
    for (int q = 0; q < 4; ++q) *(s16x8*)(zp + q * 8) = o.v[q];
  }
  if (cq == 0) {
    float4 xj = u.c.sxc[jl];
    u.c.tile[128][jl] = __float2bfloat16(m >= 0 ? 1.0f : 0.0f);
    u.c.tile[129][jl] = __float2bfloat16(m >= 0 ? xj.x : 0.f);
    u.c.tile[130][jl] = __float2bfloat16(m >= 0 ? xj.y : 0.f);
    u.c.tile[131][jl] = __float2bfloat16(m >= 0 ? xj.z : 0.f);
    __hip_bfloat16 zz = __float2bfloat16(0.0f);
    for (int rr = 132; rr < ADX; ++rr) u.c.tile[rr][jl] = zz;
  }
  __syncthreads();
  for (int i = tid; i < ADX * 2; i += 256) {
    int r = i >> 1, hf = i & 1;
    __hip_bfloat16* dst = hfTc + (size_t)b * ADX * NVP + (size_t)r * NVP + j0 + hf * 32;
    const __hip_bfloat16* srow = &u.c.tile[r][hf * 32];
    #pragma unroll
    for (int q = 0; q < 4; ++q)
      *(s16x8*)(dst + q * 8) = *(const s16x8*)(srow + q * 8);
  }
}

// ---------------- K2: compacted (w @ [hf | 1 x y z]) via MFMA bf16 ----------------
// grid = BB * NVT * KC = 448, 256 threads; 64 rows/block; nv-based early exit
__global__ __launch_bounds__(256, 4) void k_haggc(
    const float4* __restrict__ xc, const __hip_bfloat16* __restrict__ hfTc,
    __hip_bfloat16* __restrict__ haggp, float* __restrict__ dgp,
    const int* __restrict__ ws_nv) {
  constexpr int NSTEP = NVP / 32;                    // 56
  constexpr int CH_MAX = (NSTEP + KC - 1) / KC;      // 7
  __shared__ float4 xs[(CH_MAX * 4 + 1) * 9];
  __shared__ alignas(16) __hip_bfloat16 sB[2][4608];

  int bid = blockIdx.x;
  int b = bid / (NVT * KC);
  int rem = bid % (NVT * KC);
  int kc = rem / NVT;
  int nt = rem % NVT;
  int n0 = nt * 64;
  int nv = ws_nv[b];
  if (n0 >= nv) return;                              // row-tile fully invalid
  int sb = (kc * NSTEP) / KC, se = ((kc + 1) * NSTEP) / KC;
  int nstep_eff = (nv + 31) >> 5;
  int se2 = se < nstep_eff ? se : nstep_eff;         // cols >= nv give w=0 exactly
  int tid = threadIdx.x, w = tid >> 6, lane = tid & 63;
  int ln = lane & 15, g8 = (lane >> 4) * 8;

  const float4* xb = xc + b * NVP;
  const __hip_bfloat16* hb = hfTc + (size_t)b * ADX * NVP;

  float4 xn = xb[n0 + w * 16 + ln];
  float x2n = xn.w;

  f32x4 acc[9];
  #pragma unroll
  for (int ct = 0; ct < 9; ++ct) acc[ct] = (f32x4){0.f, 0.f, 0.f, 0.f};

  auto STAGE = [&](int s, int pb) {
    const char* srcb = (const char*)(hb + (size_t)s * 32);
    #pragma unroll
    for (int k = 0; k < 3; ++k) {
      int t = tid + k * 256;
      if (t < 576) {
        int row = t >> 2;
        int sl = (t & 3) ^ (row & 3);
        const gu32* gp = (const gu32*)(const void*)(srcb + (size_t)row * (NVP * 2) + sl * 16);
        lu32* lp = (lu32*)(void*)((char*)&sB[pb][0] + (size_t)(t & ~63) * 16);
        __builtin_amdgcn_global_load_lds(gp, lp, 16, 0, 0);
      }
    }
  };

  if (sb < se2) {
    int mcnt = (se2 - sb) * 32;
    for (int i = tid; i < mcnt; i += 256)
      xs[(i >> 3) * 9 + (i & 7)] = xb[sb * 32 + i];

    STAGE(sb, 0);
    __syncthreads();

    int cur = 0;
    for (int s = sb; s < se2; ++s) {
      if (s + 1 < se2) STAGE(s + 1, cur ^ 1);
      int grp = (s - sb) * 4 + (g8 >> 3);
      union { s16x8 v; __hip_bfloat16 h[8]; } af;
      #pragma unroll
      for (int j = 0; j < 8; ++j) {
        float4 xm = xs[grp * 9 + j];
        float dt = xn.x * xm.x + xn.y * xm.y + xn.z * xm.z;
        float d2 = x2n + xm.w - 2.f * dt;
        float wv = (d2 < 64.f) ? __expf(d2 * -0.0078125f) : 0.f;
        af.h[j] = __float2bfloat16(wv);
      }
      const char* bbase = (const char*)&sB[cur][0];
      int slot = g8 >> 3;
      #pragma unroll
      for (int ct = 0; ct < 9; ++ct) {
        int row = ct * 16 + ln;
        int boff = (row << 6) + ((slot ^ (row & 3)) << 4);
        s16x8 bf = *(const s16x8*)(bbase + boff);
        acc[ct] = __builtin_amdgcn_mfma_f32_16x16x32_bf16(af.v, bf, acc[ct], 0, 0, 0);
      }
      __syncthreads();
      cur ^= 1;
    }
  }

  int q = lane >> 4;
  int grow = b * NVP + n0 + w * 16 + q * 4;
  #pragma unroll
  for (int ct = 0; ct < 8; ++ct)
    #pragma unroll
    for (int r = 0; r < 4; ++r)
      haggp[((size_t)kc * NVPT + grow + r) * AD + ct * 16 + ln] = __float2bfloat16(acc[ct][r]);
  if (ln < 4)
    #pragma unroll
    for (int r = 0; r < 4; ++r)
      dgp[((size_t)kc * NVPT + grow + r) * 4 + ln] = acc[8][r];
}

// ---------------- K3: fused reduce + MLP + gate + scatter (8-wave) ----------------
// grid = NVPT/32 = 112 blocks, 512 threads; nv-based early exit
__global__ __launch_bounds__(512) void k_mlpf(
    const __hip_bfloat16* __restrict__ ws_z,
    const __hip_bfloat16* __restrict__ haggp, const float* __restrict__ dgp,
    const __hip_bfloat16* __restrict__ W1T, const float* __restrict__ b1v,
    const float* __restrict__ W2, const float* __restrict__ b2v,
    const float4* __restrict__ xc, const int* __restrict__ cg2g,
    const float* __restrict__ ws_val, float* __restrict__ out_pos,
    const int* __restrict__ ws_nv) {
  __shared__ __hip_bfloat16 zt[32][136];
  __shared__ float sai[32][4];
  __shared__ float ppart[4][32][3];

  int r0 = blockIdx.x * 32;
  int bq0 = r0 / NVP;
  if (r0 - bq0 * NVP >= ws_nv[bq0]) return;          // all rows invalid

  int tid = threadIdx.x, w = tid >> 6, lane = tid & 63;
  int ln = lane & 15, g8 = (lane >> 4) * 8, q = lane >> 4;
  int rowhalf = w & 1, js4 = w >> 1;

  if (tid < 32) {
    int g = r0 + tid;
    float deg = 0.f, wx = 0.f, wy = 0.f, wz = 0.f;
    #pragma unroll
    for (int kc = 0; kc < KC; ++kc) {
      float4 d = *(const float4*)&dgp[((size_t)kc * NVPT + g) * 4];
      deg += d.x; wx += d.y; wy += d.z; wz += d.w;
    }
    float inv = 1.f / (deg + 1.f);
    float4 xv = xc[g];
    sai[tid][0] = (xv.x * deg - wx) * inv;
    sai[tid][1] = (xv.y * deg - wy) * inv;
    sai[tid][2] = (xv.z * deg - wz) * inv;
    sai[tid][3] = inv;
  }
  __syncthreads();
  {
    int row = tid >> 4, c8 = tid & 15;
    int g = r0 + row;
    float s[8];
    #pragma unroll
    for (int j = 0; j < 8; ++j) s[j] = 0.f;
    #pragma unroll
    for (int kc = 0; kc < KC; ++kc) {
      union { s16x8 v; __hip_bfloat16 h[8]; } uu;
      uu.v = *(const s16x8*)(haggp + ((size_t)kc * NVPT + g) * AD + c8 * 8);
      #pragma unroll
      for (int j = 0; j < 8; ++j) s[j] += __bfloat162float(uu.h[j]);
    }
    float inv = sai[row][3];
    #pragma unroll
    for (int j = 0; j < 8; ++j)
      zt[row][c8 * 8 + j] = __float2bfloat16(s[j] * inv);
  }
  __syncthreads();

  int arl = rowhalf * 16 + ln;
  int arow = r0 + arl;
  s16x8 a[8];
  #pragma unroll
  for (int kq = 0; kq < 4; ++kq)
    a[kq] = *(const s16x8*)(ws_z + (size_t)arow * 128 + kq * 32 + g8);
  #pragma unroll
  for (int kq = 4; kq < 8; ++kq)
    a[kq] = *(const s16x8*)&zt[arl][(kq - 4) * 32 + g8];

  float p[4][3];
  #pragma unroll
  for (int r = 0; r < 4; ++r)
    #pragma unroll
    for (int o = 0; o < 3; ++o) p[r][o] = 0.f;

  #pragma unroll
  for (int jt = 0; jt < 8; ++jt) {
    int j = js4 * 128 + jt * 16 + ln;
    f32x4 acc = (f32x4){0.f, 0.f, 0.f, 0.f};
    #pragma unroll
    for (int kq = 0; kq < 8; ++kq) {
      s16x8 bw = *(const s16x8*)(W1T + (size_t)j * 256 + kq * 32 + g8);
      acc = __builtin_amdgcn_mfma_f32_16x16x32_bf16(a[kq], bw, acc, 0, 0, 0);
    }
    float bias = b1v[j];
    float w20 = W2[j * 3 + 0], w21 = W2[j * 3 + 1], w22 = W2[j * 3 + 2];
    #pragma unroll
    for (int r = 0; r < 4; ++r) {
      float h = fmaxf(acc[r] + bias, 0.f);
      p[r][0] += h * w20; p[r][1] += h * w21; p[r][2] += h * w22;
    }
  }
  #pragma unroll
  for (int r = 0; r < 4; ++r)
    #pragma unroll
    for (int o = 0; o < 3; ++o) {
      p[r][o] += __shfl_xor(p[r][o], 1);
      p[r][o] += __shfl_xor(p[r][o], 2);
      p[r][o] += __shfl_xor(p[r][o], 4);
      p[r][o] += __shfl_xor(p[r][o], 8);
    }
  if (ln == 0) {
    #pragma unroll
    for (int r = 0; r < 4; ++r) {
      int row = rowhalf * 16 + q * 4 + r;
      #pragma unroll
      for (int o = 0; o < 3; ++o) ppart[js4][row][o] = p[r][o];
    }
  }
  __syncthreads();

  if (tid < 32) {
    int row = tid;
    int g = r0 + row;
    int bq = g / NVP;
    int m = cg2g[g];
    if (m >= 0) {
      float p0 = b2v[0] + ppart[0][row][0] + ppart[1][row][0] + ppart[2][row][0] + ppart[3][row][0];
      float p1 = b2v[1] + ppart[0][row][1] + ppart[1][row][1] + ppart[2][row][1] + ppart[3][row][1];
      float p2 = b2v[2] + ppart[0][row][2] + ppart[1][row][2] + ppart[2][row][2] + ppart[3][row][2];
      float val = ws_val[bq * NS + m];
      float4 xv = xc[g];
      float* op = out_pos + (size_t)(bq * NS + m) * 3;
      op[0] = xv.x + sai[row][0] * tanhf(p0) * val;
      op[1] = xv.y + sai[row][1] * tanhf(p1) * val;
      op[2] = xv.z + sai[row][2] * tanhf(p2) * val;
    }
  }
}

extern "C" void kernel_launch(void* const* d_in, const int* in_sizes, int n_in,
                              void* d_out, int out_size, void* d_ws, size_t ws_size,
                              hipStream_t stream) {
  const float* bb    = (const float*)d_in[0];
  const float* sf    = (const float*)d_in[1];
  const float* aa    = (const float*)d_in[2];
  const float* mask  = (const float*)d_in[4];
  const float* pm    = (const float*)d_in[5];
  const float* emb   = (const float*)d_in[6];
  const float* W1    = (const float*)d_in[7];
  const float* b1v   = (const float*)d_in[8];
  const float* W2    = (const float*)d_in[9];
  const float* b2v   = (const float*)d_in[10];
  const float* noise = (const float*)d_in[11];

  float* out_mask = (float*)d_out;
  float* out_pos  = (float*)d_out + BB * LL * NAT;

  char* cur = (char*)d_ws;
  auto alloc = [&](size_t bytes) -> char* {
    char* p = cur;
    cur += (bytes + 255) & ~(size_t)255;
    return p;
  };
  int*    ws_nv  = (int*)alloc((size_t)BB * 4);
  float*  ws_val = (float*)alloc((size_t)TOT * 4);
  int*    cg2g   = (int*)alloc((size_t)BB * NVP * 4);
  float4* xc     = (float4*)alloc((size_t)BB * NVP * 16);
  float*  ws_dgp = (float*)alloc((size_t)KC * NVPT * 16);
  __hip_bfloat16* ws_w1t = (__hip_bfloat16*)alloc((size_t)HID * 256 * 2);
  __hip_bfloat16* hfTc   = (__hip_bfloat16*)alloc((size_t)BB * ADX * NVP * 2);
  __hip_bfloat16* haggp  = (__hip_bfloat16*)alloc((size_t)KC * NVPT * AD * 2);
  __hip_bfloat16* ws_z   = (__hip_bfloat16*)alloc((size_t)NVPT * 128 * 2);

  hipLaunchKernelGGL(k_prep, dim3(32 + BB * LL + BB * NVT), dim3(256), 0, stream,
                     W1, bb, aa, mask, pm, noise, sf, emb,
                     out_mask, out_pos, ws_w1t, ws_val, cg2g, xc, hfTc, ws_z, ws_nv);
  hipLaunchKernelGGL(k_haggc, dim3(BB * NVT * KC), dim3(256), 0, stream,
                     xc, hfTc, haggp, ws_dgp, ws_nv);
  hipLaunchKernelGGL(k_mlpf, dim3(NVPT / 32), dim3(512), 0, stream,
                     ws_z, haggp, ws_dgp, ws_w1t, b1v, W2, b2v,
                     xc, cg2g, ws_val, out_pos, ws_nv);
}